// Round 3
// baseline (807.689 us; speedup 1.0000x reference)
//
#include <hip/hip_runtime.h>
#include <math.h>

#define NBINS 36
// f32(2*pi) = 0x40C90FDB, f32(pi) = 0x40490FDB -- match np.float32 constants
#define TWO_PI_F 6.28318530717958647692f
#define PI_F     3.14159265358979323846f

// Kill FMA contraction globally: numpy performs separately-rounded mul/add.
#pragma clang fp contract(off)

// ---- fast correctly-rounded-f32 atan2 (unchanged, verified absmax==0) ------
// Octant-reduced f64 evaluation: one CR f64 division, fdlibm atan polynomial,
// Ziv rounding test with fallback to ocml atan2 on ambiguous roundings
// (~2.5e-6/pixel). Result == correctly-rounded f32 atan2 == glibc atan2f.
__device__ __forceinline__ float atan2f_cr(float fy, float fx) {
    const double gy = (double)fy, gx = (double)fx;
    const double ay = fabs(gy), ax = fabs(gx);
    const double mx = fmax(ax, ay), mn = fmin(ax, ay);
    const bool hi = mn > 0.41421356237309503 * mx;   // tan(pi/8)
    const double num = hi ? mn - mx : mn;            // u <= 0 in hi branch
    const double den = hi ? mn + mx : mx;
    const double u = num / den;                      // |u| <= 0.41422, CR div
    const double z = u * u;
    const double w = z * z;
    const double s1 = z * __builtin_fma(w, __builtin_fma(w, __builtin_fma(w,
        __builtin_fma(w, __builtin_fma(w, 1.62858201153657823623e-02,
                                          4.97687799461593236017e-02),
                                          6.66107313738753120669e-02),
                                          9.09088713343650656196e-02),
                                          1.42857142725034663711e-01),
                                          3.33333333333329318027e-01);
    const double s2 = w * __builtin_fma(w, __builtin_fma(w, __builtin_fma(w,
        __builtin_fma(w, -3.65315727442169155270e-02,
                         -5.83357013379057348645e-02),
                         -7.69187620504482999495e-02),
                         -1.11111104054623557880e-01),
                         -1.99999999998764832476e-01);
    double phi = u - u * (s1 + s2);                  // atan(u), rel err ~ulp
    if (hi) phi = 0.78539816339744830962 + phi;      // pi/4 + atan(u)
    if (ay > ax) phi = 1.57079632679489661923 - phi; // first-quadrant angle
    if (__float_as_uint(fx) & 0x80000000u)           // gx negative (or -0)
        phi = 3.14159265358979323846 - phi;
    if (__float_as_uint(fy) & 0x80000000u)           // sign of gy (incl. -0)
        phi = -phi;
    const float c1 = (float)(phi * (1.0 - 7.5e-14));
    const float c2 = (float)(phi * (1.0 + 7.5e-14));
    if (__builtin_expect(c1 != c2, 0))
        return (float)atan2(gy, gx);                 // exact fallback, rare
    return c1;
}

// Block = 32 patches, 192 threads.
//   waves 1-2 (tid 64..191): phase 1 -- 4 threads/patch (2 rows x 2 half-rows),
//     per-pixel (weight,bin) records, bit-exact f32 math (identical to prior
//     verified kernel). Records double-buffered across chunks (buf = ch&1).
//   wave 0: software-pipelined replay + row prefetch:
//     interval A (concurrent with phase 1 of chunk ch):
//       - issue 8x global_load_dwordx4 for rows 2ch+3, 2ch+4 (regs)
//       - lanes 0..31: replay chunk ch-1's records in raster pixel order with
//         ds_add_f32 (one wave's DS ops execute in order => accumulation order
//         is exactly numpy's sequential np.add.at order) -- now OFF the
//         critical path, hidden under phase 1.
//     interval B (short, after barrier): ds_write prefetched rows into the
//       4-row rolling window (reads in A / writes in B are barrier-separated,
//       so the 4-slot lifetime argument is unchanged).
// After the loop: one trailing replay for chunk 15, then the epilogue.
__global__ __launch_bounds__(192, 4) void orient_kernel(
    const float* __restrict__ x,
    const float* __restrict__ gxw_p,
    const float* __restrict__ gyw_p,
    const float* __restrict__ sww_p,
    const float* __restrict__ gk,
    float* __restrict__ out)
{
#pragma clang fp contract(off)
    __shared__ float          rowbuf[4][32][33];      // rolling row window
    __shared__ float          w_rec[2][2][32][33];    // [chunk-buf][row][patch][col]
    __shared__ unsigned char  bin_rec[2][2][32][33];
    __shared__ float          acc[32][37];            // per-patch 36-bin histogram
    __shared__ float          gk_s[1024];

    const int tid = threadIdx.x;
    const size_t patch0 = (size_t)blockIdx.x * 32;

    const float gw0 = gxw_p[0], gw1 = gxw_p[1], gw2 = gxw_p[2];
    const float vw0 = gyw_p[0], vw1 = gyw_p[1], vw2 = gyw_p[2];

    // stage gk, init acc, preload rows 0..2 into slots 0..2
    for (int i = tid; i < 256; i += 192)
        ((float4*)gk_s)[i] = ((const float4*)gk)[i];
    for (int i = tid; i < 32 * 37; i += 192) ((float*)acc)[i] = 0.0f;
    for (int k = tid; k < 768; k += 192) {           // 3 rows x 32 patches x 8 f4
        const int row = k >> 8;
        const int rem = k & 255;
        const int pp  = rem >> 3;
        const int c4  = rem & 7;
        const float4 v = *((const float4*)(x + (patch0 + pp) * 1024 + row * 32 + c4 * 4));
        float* dst = &rowbuf[row][pp][c4 * 4];
        dst[0] = v.x; dst[1] = v.y; dst[2] = v.z; dst[3] = v.w;
    }
    __syncthreads();

    const int pt = tid - 64;       // phase-1 thread index (waves 1-2)
    const int p  = pt >> 2;        // patch within block
    const int q  = pt & 3;
    const int rr = q >> 1;         // row within chunk (0/1)
    const int c0 = (q & 1) << 4;   // half-row start col

    for (int ch = 0; ch < 16; ++ch) {
        float4 pre[8];
        if (tid < 64) {
            // ---- wave 0, interval A: prefetch-issue + replay chunk ch-1 ----
            if (ch < 15) {
#pragma unroll
                for (int j = 0; j < 8; ++j) {
                    const int k    = tid + 64 * j;        // 0..511
                    const int rowi = 2 * ch + 3 + (k >> 8);
                    const int srow = rowi > 31 ? 31 : rowi;
                    const int rem  = k & 255;
                    const int pp   = rem >> 3;
                    const int c4   = rem & 7;
                    pre[j] = *((const float4*)(x + (patch0 + pp) * 1024 + srow * 32 + c4 * 4));
                }
            }
            if (ch > 0 && tid < 32) {
                const int b = (ch - 1) & 1;
                for (int rm = 0; rm < 2; ++rm) {
                    for (int c = 0; c < 32; ++c) {
                        const float wv = w_rec[b][rm][tid][c];
                        const int   bv = bin_rec[b][rm][tid][c];
                        atomicAdd(&acc[tid][bv], wv);     // ds_add_f32, in order
                    }
                }
            }
        } else {
            // ------------- phase 1: records for rows 2ch, 2ch+1 -------------
            const int r  = 2 * ch + rr;
            const int su = (r == 0) ? 0 : ((r - 1) & 3);  // replicate at top
            const int sc = r & 3;
            const int sd = (r + 1) & 3;                   // slot holds row min(r+1,31)
            const int bf = ch & 1;
            float ctr  = rowbuf[sc][p][c0];
            float left = (c0 == 0) ? ctr : rowbuf[sc][p][c0 - 1];
            for (int i = 0; i < 16; ++i) {
                const int c = c0 + i;
                const float up    = rowbuf[su][p][c];
                const float dn    = rowbuf[sd][p][c];
                const float right = (c == 31) ? ctr : rowbuf[sc][p][c + 1];
                // bit-exact f32: left-assoc, no contraction
                float gx  = gw0 * left + gw1 * ctr + gw2 * right;
                float gy  = vw0 * up   + vw1 * ctr + vw2 * dn;
                float ss  = gx * gx + gy * gy + 1e-10f;
                float mag = sqrtf(ss) * gk_s[(r << 5) + c];
                float wgt = 0.0f;
                int   bin = 0;
                if (mag > 0.001f) {   // masked pixels add exactly +0.0 to bin 0
                    float o = atan2f_cr(gy, gx);          // CR f32 atan2
                    if (o < 0.0f) o += TWO_PI_F;          // np.mod(ori, 2pi)
                    float obig = (36.0f * o) / TWO_PI_F;  // f32 mul then f32 div
                    float bof  = floorf(obig);
                    float fr   = obig - bof;              // exact
                    bin = (int)bof;
                    if (bin >= NBINS) bin = 0;            // obig can round to 36.0
                    wgt = (1.0f - fr) * mag;
                }
                w_rec[bf][rr][p][c]   = wgt;
                bin_rec[bf][rr][p][c] = (unsigned char)bin;
                left = ctr; ctr = right;
            }
        }
        __syncthreads();

        // ---- interval B: wave 0 commits prefetched rows to rolling window ----
        if (tid < 64 && ch < 15) {
#pragma unroll
            for (int j = 0; j < 8; ++j) {
                const int k    = tid + 64 * j;
                const int rowi = 2 * ch + 3 + (k >> 8);
                const int slot = rowi & 3;
                const int rem  = k & 255;
                const int pp   = rem >> 3;
                const int c4   = rem & 7;
                float* dst = &rowbuf[slot][pp][c4 * 4];
                dst[0] = pre[j].x; dst[1] = pre[j].y; dst[2] = pre[j].z; dst[3] = pre[j].w;
            }
        }
        __syncthreads();
    }

    // trailing replay: chunk 15's records (buf 1), same wave, same order
    if (tid < 32) {
        for (int rm = 0; rm < 2; ++rm) {
            for (int c = 0; c < 32; ++c) {
                const float wv = w_rec[1][rm][tid][c];
                const int   bv = bin_rec[1][rm][tid][c];
                atomicAdd(&acc[tid][bv], wv);
            }
        }
    }
    __syncthreads();

    // ------- epilogue: /1024 (exact), 3-tap zero-padded smooth, argmax -------
    if (tid < 32) {
        const float s0 = sww_p[0], s1 = sww_p[1], s2 = sww_p[2];
        float hprev = 0.0f;
        float hc    = acc[tid][0] * (1.0f / 1024.0f);
        float best  = -1e30f;
        int   bi    = 0;
        for (int i = 0; i < NBINS; ++i) {
            const float hn = (i < NBINS - 1) ? acc[tid][i + 1] * (1.0f / 1024.0f) : 0.0f;
            const float sm = s0 * hprev + s1 * hc + s2 * hn;   // left-assoc, no FMA
            if (sm > best) { best = sm; bi = i; }              // first occurrence
            hprev = hc; hc = hn;
        }
        float t = TWO_PI_F * (float)bi;
        t = t / 36.0f;
        out[patch0 + tid] = -(t - PI_F);
    }
}

extern "C" void kernel_launch(void* const* d_in, const int* in_sizes, int n_in,
                              void* d_out, int out_size, void* d_ws, size_t ws_size,
                              hipStream_t stream) {
    const float* x   = (const float*)d_in[0];
    const float* gxw = (const float*)d_in[1];
    const float* gyw = (const float*)d_in[2];
    const float* sw  = (const float*)d_in[3];
    const float* gk  = (const float*)d_in[4];
    float* out = (float*)d_out;

    const int nblocks = out_size / 32;   // 65536 patches, 32 per block
    orient_kernel<<<nblocks, 192, 0, stream>>>(x, gxw, gyw, sw, gk, out);
}

// Round 4
// 708.104 us; speedup vs baseline: 1.1406x; 1.1406x over previous
//
#include <hip/hip_runtime.h>
#include <math.h>

#define NBINS 36
// f32(2*pi) = 0x40C90FDB, f32(pi) = 0x40490FDB -- match np.float32 constants
#define TWO_PI_F 6.28318530717958647692f
#define PI_F     3.14159265358979323846f

// Kill FMA contraction globally: numpy performs separately-rounded mul/add.
#pragma clang fp contract(off)

// ---- fast correctly-rounded-f32 atan2 (unchanged, verified absmax==0) ------
// Octant-reduced f64 evaluation: one CR f64 division, fdlibm atan polynomial,
// Ziv rounding test with fallback to ocml atan2 on ambiguous roundings
// (~2.5e-6/pixel). Result == correctly-rounded f32 atan2 == glibc atan2f.
__device__ __forceinline__ float atan2f_cr(float fy, float fx) {
    const double gy = (double)fy, gx = (double)fx;
    const double ay = fabs(gy), ax = fabs(gx);
    const double mx = fmax(ax, ay), mn = fmin(ax, ay);
    const bool hi = mn > 0.41421356237309503 * mx;   // tan(pi/8)
    const double num = hi ? mn - mx : mn;            // u <= 0 in hi branch
    const double den = hi ? mn + mx : mx;
    const double u = num / den;                      // |u| <= 0.41422, CR div
    const double z = u * u;
    const double w = z * z;
    const double s1 = z * __builtin_fma(w, __builtin_fma(w, __builtin_fma(w,
        __builtin_fma(w, __builtin_fma(w, 1.62858201153657823623e-02,
                                          4.97687799461593236017e-02),
                                          6.66107313738753120669e-02),
                                          9.09088713343650656196e-02),
                                          1.42857142725034663711e-01),
                                          3.33333333333329318027e-01);
    const double s2 = w * __builtin_fma(w, __builtin_fma(w, __builtin_fma(w,
        __builtin_fma(w, -3.65315727442169155270e-02,
                         -5.83357013379057348645e-02),
                         -7.69187620504482999495e-02),
                         -1.11111104054623557880e-01),
                         -1.99999999998764832476e-01);
    double phi = u - u * (s1 + s2);                  // atan(u), rel err ~ulp
    if (hi) phi = 0.78539816339744830962 + phi;      // pi/4 + atan(u)
    if (ay > ax) phi = 1.57079632679489661923 - phi; // first-quadrant angle
    if (__float_as_uint(fx) & 0x80000000u)           // gx negative (or -0)
        phi = 3.14159265358979323846 - phi;
    if (__float_as_uint(fy) & 0x80000000u)           // sign of gy (incl. -0)
        phi = -phi;
    const float c1 = (float)(phi * (1.0 - 7.5e-14));
    const float c2 = (float)(phi * (1.0 + 7.5e-14));
    if (__builtin_expect(c1 != c2, 0))
        return (float)atan2(gy, gx);                 // exact fallback, rare
    return c1;
}

// Block = 32 patches, 256 threads (8 per patch: 2 rows x 4 col-strips of 8).
// Same phase structure as the verified Round-2 kernel, shrunk so LDS = 36.3 KB
// -> 4 blocks/CU (16 waves/CU, 4/SIMD) instead of 2 -> VALU latency hidden by
// occupancy instead of (failed) intra-block pipelining.
// Phase 1 (all 4 waves): per-pixel (weight, bin) records, bit-exact f32:
//   - gradients left-assoc, no FMA
//   - mag = sqrtf((gx*gx + gy*gy) + 1e-10f) * gk
//   - orientation: CR f32 atan2 (octant-reduced f64 + Ziv fallback)
// Phase 2 (wave 0, lanes 0-31, lane = patch): replay chunk's records in raster
//   pixel order with ds_add_f32; one wave's DS ops execute in order => exact
//   numpy np.add.at accumulation order. Waves 1-3 preload next 2 rows.
__global__ __launch_bounds__(256, 4) void orient_kernel(
    const float* __restrict__ x,
    const float* __restrict__ gxw_p,
    const float* __restrict__ gyw_p,
    const float* __restrict__ sww_p,
    const float* __restrict__ gk,
    float* __restrict__ out)
{
#pragma clang fp contract(off)
    __shared__ float          rowbuf[4][32][33];   // rolling row window, slot = row % 4
    __shared__ float          w_rec[2][32][33];    // per-chunk records: weight
    __shared__ unsigned char  bin_rec[2][32][33];  // per-chunk records: bin
    __shared__ float          acc[32][37];         // per-patch 36-bin histogram
    __shared__ float          gk_s[1024];

    const int tid = threadIdx.x;
    const size_t patch0 = (size_t)blockIdx.x * 32;

    const float gw0 = gxw_p[0], gw1 = gxw_p[1], gw2 = gxw_p[2];
    const float vw0 = gyw_p[0], vw1 = gyw_p[1], vw2 = gyw_p[2];

    // stage gk, init acc, preload rows 0..2 into slots 0..2
    ((float4*)gk_s)[tid] = ((const float4*)gk)[tid];
    for (int i = tid; i < 32 * 37; i += 256) ((float*)acc)[i] = 0.0f;
    for (int k = tid; k < 768; k += 256) {          // 3 rows x 32 patches x 8 f4
        const int row = k >> 8;
        const int rem = k & 255;
        const int pp  = rem >> 3;
        const int c4  = rem & 7;
        const float4 v = *((const float4*)(x + (patch0 + pp) * 1024 + row * 32 + c4 * 4));
        float* dst = &rowbuf[row][pp][c4 * 4];
        dst[0] = v.x; dst[1] = v.y; dst[2] = v.z; dst[3] = v.w;
    }
    __syncthreads();

    const int p  = tid >> 3;       // patch within block (0..31)
    const int q  = tid & 7;
    const int rr = q >> 2;         // row within chunk (0/1)
    const int c0 = (q & 3) << 3;   // col-strip start: 0,8,16,24

    for (int ch = 0; ch < 16; ++ch) {
        // ---------------- phase 1: records for rows 2ch, 2ch+1 ----------------
        {
            const int r  = 2 * ch + rr;
            const int su = (r == 0) ? 0 : ((r - 1) & 3);  // replicate at top
            const int sc = r & 3;
            const int sd = (r + 1) & 3;                   // slot holds row min(r+1,31)
            float ctr  = rowbuf[sc][p][c0];
            float left = (c0 == 0) ? ctr : rowbuf[sc][p][c0 - 1];
            for (int i = 0; i < 8; ++i) {
                const int c = c0 + i;
                const float up    = rowbuf[su][p][c];
                const float dn    = rowbuf[sd][p][c];
                const float right = (c == 31) ? ctr : rowbuf[sc][p][c + 1];
                // bit-exact f32: left-assoc, no contraction
                float gx  = gw0 * left + gw1 * ctr + gw2 * right;
                float gy  = vw0 * up   + vw1 * ctr + vw2 * dn;
                float ss  = gx * gx + gy * gy + 1e-10f;
                float mag = sqrtf(ss) * gk_s[(r << 5) + c];
                float wgt = 0.0f;
                int   bin = 0;
                if (mag > 0.001f) {   // masked pixels add exactly +0.0 to bin 0
                    float o = atan2f_cr(gy, gx);          // CR f32 atan2
                    if (o < 0.0f) o += TWO_PI_F;          // np.mod(ori, 2pi)
                    float obig = (36.0f * o) / TWO_PI_F;  // f32 mul then f32 div
                    float bof  = floorf(obig);
                    float fr   = obig - bof;              // exact
                    bin = (int)bof;
                    if (bin >= NBINS) bin = 0;            // obig can round to 36.0
                    wgt = (1.0f - fr) * mag;
                }
                w_rec[rr][p][c]   = wgt;
                bin_rec[rr][p][c] = (unsigned char)bin;
                left = ctr; ctr = right;
            }
        }
        __syncthreads();

        // ---------- phase 2: ordered accumulate | preload next 2 rows ----------
        if (tid < 32) {
            // lane = patch; one wave's DS ops execute in order -> exact raster-order
            // sequential f32 accumulation (numpy np.add.at order).
            for (int rm = 0; rm < 2; ++rm) {
                for (int c = 0; c < 32; ++c) {
                    const float wv = w_rec[rm][tid][c];
                    const int   bv = bin_rec[rm][tid][c];
                    atomicAdd(&acc[tid][bv], wv);         // ds_add_f32
                }
            }
        } else if (tid >= 64 && ch < 15) {
            // waves 1-3: prefetch rows 2ch+3, 2ch+4 (512 float4s over 192 thr)
            for (int k = tid - 64; k < 512; k += 192) {
                const int rowi = 2 * ch + 3 + (k >> 8);
                const int srow = rowi > 31 ? 31 : rowi;
                const int slot = rowi & 3;
                const int rem  = k & 255;
                const int pp   = rem >> 3;
                const int c4   = rem & 7;
                const float4 v = *((const float4*)(x + (patch0 + pp) * 1024 + srow * 32 + c4 * 4));
                float* dst = &rowbuf[slot][pp][c4 * 4];
                dst[0] = v.x; dst[1] = v.y; dst[2] = v.z; dst[3] = v.w;
            }
        }
        __syncthreads();
    }

    // ------- epilogue: /1024 (exact), 3-tap zero-padded smooth, argmax -------
    if (tid < 32) {
        const float s0 = sww_p[0], s1 = sww_p[1], s2 = sww_p[2];
        float hprev = 0.0f;
        float hc    = acc[tid][0] * (1.0f / 1024.0f);
        float best  = -1e30f;
        int   bi    = 0;
        for (int i = 0; i < NBINS; ++i) {
            const float hn = (i < NBINS - 1) ? acc[tid][i + 1] * (1.0f / 1024.0f) : 0.0f;
            const float sm = s0 * hprev + s1 * hc + s2 * hn;   // left-assoc, no FMA
            if (sm > best) { best = sm; bi = i; }              // first occurrence
            hprev = hc; hc = hn;
        }
        float t = TWO_PI_F * (float)bi;
        t = t / 36.0f;
        out[patch0 + tid] = -(t - PI_F);
    }
}

extern "C" void kernel_launch(void* const* d_in, const int* in_sizes, int n_in,
                              void* d_out, int out_size, void* d_ws, size_t ws_size,
                              hipStream_t stream) {
    const float* x   = (const float*)d_in[0];
    const float* gxw = (const float*)d_in[1];
    const float* gyw = (const float*)d_in[2];
    const float* sw  = (const float*)d_in[3];
    const float* gk  = (const float*)d_in[4];
    float* out = (float*)d_out;

    const int nblocks = out_size / 32;   // 65536 patches, 32 per block
    orient_kernel<<<nblocks, 256, 0, stream>>>(x, gxw, gyw, sw, gk, out);
}